// Round 8
// baseline (251.813 us; speedup 1.0000x reference)
//
#include <hip/hip_runtime.h>
#include <hip/hip_bf16.h>
#include <math.h>

// Problem constants (B,S,H fixed by setup_inputs)
constexpr int Bc = 4, Sc = 2048, Hc = 1024, NHc = 16, DKc = 64;

// Workspace layout (float units). Total ~61 MB.
constexpr size_t XHOFF = 0;                 // x bf16: 8,388,608 shorts
constexpr size_t QOFF  = 4194304;           // Q bf16 (bh,s,d)
constexpr size_t KOFF  = 8388608;           // K bf16 (bh,s,d)
constexpr size_t WQOFF = 12582912;          // Wq bf16 (pre-scaled 0.125)
constexpr size_t WKOFF = 13107200;          // Wk bf16
constexpr size_t LIOFF = 13631488;          // 1/rowsum per (bh,q)
constexpr size_t WOFF  = 13762560;          // attn column sums per (bh,k)
constexpr size_t YOFF  = 13893632;          // y[b,h,j] fp32 (4*16*1024)
constexpr size_t CSOFF = 13959168;          // csum[b,n] (4*1024)
constexpr size_t YPOFF = 13963264;          // y partials: 16 chunks x 65536
constexpr size_t RPOFF = 15011840;          // rowsum partials: 4*64*2048
constexpr size_t CPOFF = 15536128;          // colsum partials: 4*64*2048

typedef __attribute__((ext_vector_type(8))) short bf16x8;  // 8 bf16 (4 VGPRs)
typedef __attribute__((ext_vector_type(4))) float f32x4;

__device__ inline short f2bf(float v) {
    __hip_bfloat16 h = __float2bfloat16(v);
    return *reinterpret_cast<short*>(&h);
}

__device__ inline void gld_lds16(const void* g, void* l) {
    __builtin_amdgcn_global_load_lds(
        (const __attribute__((address_space(1))) unsigned int*)g,
        (__attribute__((address_space(3))) unsigned int*)l, 16, 0, 0);
}

// ---------------------------------------------------------------------------
// Kernel 0: fused fp32 -> bf16 conversion of x / Wq(x0.125) / Wk.
// ---------------------------------------------------------------------------
__global__ __launch_bounds__(256) void cvt_all_kernel(
    const float* __restrict__ x, const float* __restrict__ Wq,
    const float* __restrict__ Wk, float* __restrict__ ws)
{
    const size_t i = ((size_t)blockIdx.x * 256 + threadIdx.x) * 8;
    const float* src; short* dst; float scale; size_t off;
    if (i < 8388608)       { src = x;  dst = (short*)(ws + XHOFF); off = i;            scale = 1.0f;   }
    else if (i < 9437184)  { src = Wq; dst = (short*)(ws + WQOFF); off = i - 8388608;  scale = 0.125f; }
    else                   { src = Wk; dst = (short*)(ws + WKOFF); off = i - 9437184;  scale = 1.0f;   }
    float4 a = *(const float4*)(src + off);
    float4 b = *(const float4*)(src + off + 4);
    bf16x8 o;
    o[0] = f2bf(a.x * scale); o[1] = f2bf(a.y * scale);
    o[2] = f2bf(a.z * scale); o[3] = f2bf(a.w * scale);
    o[4] = f2bf(b.x * scale); o[5] = f2bf(b.y * scale);
    o[6] = f2bf(b.z * scale); o[7] = f2bf(b.w * scale);
    *(bf16x8*)(dst + off) = o;
}

// ---------------------------------------------------------------------------
// Kernel 1: Q/K projections, bf16 MFMA, m97-style 128x128 tile.
// ---------------------------------------------------------------------------
__global__ __launch_bounds__(256) void proj_mfma_kernel(
    const int* __restrict__ L, float* __restrict__ ws)
{
    const int z  = blockIdx.z;
    const int m0 = blockIdx.y * 128;
    const int n0 = blockIdx.x * 128;
    const int b  = m0 >> 11;
    const int s0 = m0 & 2047;
    const int Lb = L[b];
    if (s0 >= Lb) return;

    const short* __restrict__ A = (const short*)(ws + XHOFF);
    const short* __restrict__ W = (const short*)(ws + (z == 0 ? WQOFF : WKOFF));
    short* __restrict__ Out = (short*)(ws + (z == 0 ? QOFF : KOFF));

    __shared__ __align__(16) short As[128 * 32];
    __shared__ __align__(16) short Bs[128 * 32];

    const int tid  = threadIdx.x;
    const int lane = tid & 63;
    const int wave = tid >> 6;
    const int l16  = lane & 15, quad = lane >> 4;
    const int wm = (wave & 1) * 64, wn = (wave >> 1) * 64;

    const int c0 = tid, c1 = tid + 256;
    const int r0 = c0 >> 2, g0 = (c0 & 3) * 8;
    const int r1 = c1 >> 2, g1 = (c1 & 3) * 8;
    short* lA0 = As + wave * 512;
    short* lA1 = As + 2048 + wave * 512;
    short* lB0 = Bs + wave * 512;
    short* lB1 = Bs + 2048 + wave * 512;

    const f32x4 z4 = {0.f, 0.f, 0.f, 0.f};
    f32x4 acc[4][4];
    #pragma unroll
    for (int i = 0; i < 4; ++i)
        #pragma unroll
        for (int j = 0; j < 4; ++j) acc[i][j] = z4;

    for (int k0 = 0; k0 < Hc; k0 += 32) {
        __syncthreads();
        gld_lds16(A + (size_t)(m0 + r0) * Hc + k0 + g0, lA0);
        gld_lds16(A + (size_t)(m0 + r1) * Hc + k0 + g1, lA1);
        gld_lds16(W + (size_t)(n0 + r0) * Hc + k0 + g0, lB0);
        gld_lds16(W + (size_t)(n0 + r1) * Hc + k0 + g1, lB1);
        __syncthreads();

        bf16x8 af[4], bfr[4];
        #pragma unroll
        for (int mt = 0; mt < 4; ++mt)
            af[mt] = *(const bf16x8*)(As + (wm + mt * 16 + l16) * 32 + quad * 8);
        #pragma unroll
        for (int nt = 0; nt < 4; ++nt)
            bfr[nt] = *(const bf16x8*)(Bs + (wn + nt * 16 + l16) * 32 + quad * 8);
        #pragma unroll
        for (int mt = 0; mt < 4; ++mt)
            #pragma unroll
            for (int nt = 0; nt < 4; ++nt)
                acc[mt][nt] = __builtin_amdgcn_mfma_f32_16x16x32_bf16(
                    af[mt], bfr[nt], acc[mt][nt], 0, 0, 0);
    }

    #pragma unroll
    for (int mt = 0; mt < 4; ++mt) {
        #pragma unroll
        for (int nt = 0; nt < 4; ++nt) {
            const int n = n0 + wn + nt * 16 + l16;
            const int h = n >> 6, d = n & 63;
            #pragma unroll
            for (int r = 0; r < 4; ++r) {
                const int s = s0 + wm + mt * 16 + quad * 4 + r;
                Out[(((size_t)b * NHc + h) * Sc + s) * DKc + d] =
                    f2bf(acc[mt][nt][r]);
            }
        }
    }
}

// ---------------------------------------------------------------------------
// Kernel 2a: partial row sums over a 512-key chunk; double-buffered 128-row
// LDS K stages (stage i+1 loads issued before stage i compute -> the
// end-of-stage barrier's vmcnt drain finds them complete).
// ---------------------------------------------------------------------------
__global__ __launch_bounds__(256) void rowsum_part_kernel(
    const int* __restrict__ L, float* __restrict__ ws)
{
    const int bh = blockIdx.x;
    const int b  = bh >> 4;
    const int Lb = L[b];
    const int kc0 = blockIdx.z * 512;
    if (blockIdx.y * 128 >= Lb || kc0 >= Lb) return;

    const int tid  = threadIdx.x;
    const int wave = tid >> 6;
    const int lane = tid & 63;
    const int q0 = blockIdx.y * 128 + wave * 32;
    const int l16 = lane & 15, quad = lane >> 4;

    const short* __restrict__ qarr = (const short*)(ws + QOFF) + (size_t)bh * Sc * DKc;
    const short* __restrict__ karr = (const short*)(ws + KOFF) + (size_t)bh * Sc * DKc;

    __shared__ __align__(16) short Ks[2][128 * 64];   // 2 x 16 KB, swizzled

    const short* qrow0 = qarr + (size_t)(q0 + l16) * DKc;
    const short* qrow1 = qarr + (size_t)(q0 + 16 + l16) * DKc;
    const bf16x8 b0lo = *(const bf16x8*)(qrow0 + quad * 8);
    const bf16x8 b0hi = *(const bf16x8*)(qrow0 + 32 + quad * 8);
    const bf16x8 b1lo = *(const bf16x8*)(qrow1 + quad * 8);
    const bf16x8 b1hi = *(const bf16x8*)(qrow1 + 32 + quad * 8);

    const int kend = (kc0 + 512 < Lb) ? kc0 + 512 : Lb;
    const int nst  = (kend - kc0 + 127) >> 7;

    const int srow = tid >> 3;                 // this thread's staged row slot
    const int scc  = tid & 7;
    const int sc_  = scc ^ (srow & 7);         // swizzled source chunk

    // prologue: stage 0
    #pragma unroll
    for (int i = 0; i < 4; ++i) {
        const int s = i * 256 + tid;
        const int row = s >> 3, c = (s & 7) ^ (row & 7);
        gld_lds16(karr + (size_t)(kc0 + row) * DKc + c * 8,
                  &Ks[0][(i * 256 + wave * 64) * 8]);
    }

    float lacc0 = 0.f, lacc1 = 0.f;
    for (int st = 0; st < nst; ++st) {
        __syncthreads();                       // publishes buf[st&1]
        if (st + 1 < nst) {
            const int ktn = kc0 + (st + 1) * 128;
            #pragma unroll
            for (int i = 0; i < 4; ++i) {
                const int s = i * 256 + tid;
                const int row = s >> 3, c = (s & 7) ^ (row & 7);
                gld_lds16(karr + (size_t)(ktn + row) * DKc + c * 8,
                          &Ks[(st + 1) & 1][(i * 256 + wave * 64) * 8]);
            }
        }
        const short* Kb = Ks[st & 1];
        const int kt = kc0 + st * 128;
        #pragma unroll
        for (int t = 0; t < 8; ++t) {
            const int r = t * 16 + l16;
            const bf16x8 alo = *(const bf16x8*)(Kb + (r * 8 + (quad ^ (r & 7))) * 8);
            const bf16x8 ahi = *(const bf16x8*)(Kb + (r * 8 + ((4 + quad) ^ (r & 7))) * 8);
            f32x4 c0 = {0.f, 0.f, 0.f, 0.f}, c1 = {0.f, 0.f, 0.f, 0.f};
            c0 = __builtin_amdgcn_mfma_f32_16x16x32_bf16(alo, b0lo, c0, 0, 0, 0);
            c0 = __builtin_amdgcn_mfma_f32_16x16x32_bf16(ahi, b0hi, c0, 0, 0, 0);
            c1 = __builtin_amdgcn_mfma_f32_16x16x32_bf16(alo, b1lo, c1, 0, 0, 0);
            c1 = __builtin_amdgcn_mfma_f32_16x16x32_bf16(ahi, b1hi, c1, 0, 0, 0);
            #pragma unroll
            for (int rr = 0; rr < 4; ++rr) {
                const bool kv = (kt + t * 16 + quad * 4 + rr) < kend;
                lacc0 += kv ? __expf(c0[rr]) : 0.f;
                lacc1 += kv ? __expf(c1[rr]) : 0.f;
            }
        }
    }
    (void)srow; (void)sc_;
    lacc0 += __shfl_xor(lacc0, 16, 64); lacc0 += __shfl_xor(lacc0, 32, 64);
    lacc1 += __shfl_xor(lacc1, 16, 64); lacc1 += __shfl_xor(lacc1, 32, 64);
    float* __restrict__ rp = ws + RPOFF + ((size_t)blockIdx.z * 64 + bh) * Sc;
    if (quad == 0) rp[q0 + l16]      = lacc0;
    if (quad == 1) rp[q0 + 16 + l16] = lacc1;
}

// ---------------------------------------------------------------------------
// Kernel 2b: liarr[q] = 1 / sum over valid k-chunks of rp.
// ---------------------------------------------------------------------------
__global__ __launch_bounds__(256) void rowsum_reduce_kernel(
    const int* __restrict__ L, float* __restrict__ ws)
{
    const int bh = blockIdx.y;
    const int q  = blockIdx.x * 256 + threadIdx.x;
    const int nc = (L[bh >> 4] + 511) >> 9;
    float acc = 0.f;
    for (int c = 0; c < nc; ++c)
        acc += ws[RPOFF + ((size_t)c * 64 + bh) * Sc + q];
    ws[LIOFF + (size_t)bh * Sc + q] = 1.0f / acc;
}

// ---------------------------------------------------------------------------
// Kernel 3a: partial column sums over a 512-query chunk; double-buffered
// 128-row LDS Q stages (same pipeline as rowsum_part).
// ---------------------------------------------------------------------------
__global__ __launch_bounds__(256) void colsum_part_kernel(
    const int* __restrict__ L, float* __restrict__ ws)
{
    const int bh = blockIdx.x;
    const int b  = bh >> 4;
    const int Lb = L[b];
    const int qc0 = blockIdx.z * 512;
    if (blockIdx.y * 128 >= Lb || qc0 >= Lb) return;

    const int tid  = threadIdx.x;
    const int wave = tid >> 6;
    const int lane = tid & 63;
    const int k0 = blockIdx.y * 128 + wave * 32;
    const int l16 = lane & 15, quad = lane >> 4;

    const short* __restrict__ qarr = (const short*)(ws + QOFF) + (size_t)bh * Sc * DKc;
    const short* __restrict__ karr = (const short*)(ws + KOFF) + (size_t)bh * Sc * DKc;
    const float* __restrict__ liarr = ws + LIOFF + (size_t)bh * Sc;

    __shared__ __align__(16) short Qs[2][128 * 64];   // 2 x 16 KB, swizzled
    __shared__ __align__(16) float Lis[2][128];

    const short* krow0 = karr + (size_t)(k0 + l16) * DKc;
    const short* krow1 = karr + (size_t)(k0 + 16 + l16) * DKc;
    const bf16x8 a0lo = *(const bf16x8*)(krow0 + quad * 8);
    const bf16x8 a0hi = *(const bf16x8*)(krow0 + 32 + quad * 8);
    const bf16x8 a1lo = *(const bf16x8*)(krow1 + quad * 8);
    const bf16x8 a1hi = *(const bf16x8*)(krow1 + 32 + quad * 8);

    const int qend = (qc0 + 512 < Lb) ? qc0 + 512 : Lb;
    const int nst  = (qend - qc0 + 127) >> 7;

    // prologue: stage 0
    #pragma unroll
    for (int i = 0; i < 4; ++i) {
        const int s = i * 256 + tid;
        const int row = s >> 3, c = (s & 7) ^ (row & 7);
        gld_lds16(qarr + (size_t)(qc0 + row) * DKc + c * 8,
                  &Qs[0][(i * 256 + wave * 64) * 8]);
    }
    if (tid < 32) gld_lds16(liarr + qc0 + tid * 4, &Lis[0][0]);

    float w0[4] = {0.f, 0.f, 0.f, 0.f};
    float w1[4] = {0.f, 0.f, 0.f, 0.f};

    for (int st = 0; st < nst; ++st) {
        __syncthreads();                       // publishes buf[st&1]
        if (st + 1 < nst) {
            const int qtn = qc0 + (st + 1) * 128;
            #pragma unroll
            for (int i = 0; i < 4; ++i) {
                const int s = i * 256 + tid;
                const int row = s >> 3, c = (s & 7) ^ (row & 7);
                gld_lds16(qarr + (size_t)(qtn + row) * DKc + c * 8,
                          &Qs[(st + 1) & 1][(i * 256 + wave * 64) * 8]);
            }
            if (tid < 32) gld_lds16(liarr + qtn + tid * 4, &Lis[(st + 1) & 1][0]);
        }
        const short* Qb = Qs[st & 1];
        const float* Lb_ = Lis[st & 1];
        const int qt = qc0 + st * 128;
        #pragma unroll
        for (int t = 0; t < 8; ++t) {
            const int r = t * 16 + l16;
            const bf16x8 blo = *(const bf16x8*)(Qb + (r * 8 + (quad ^ (r & 7))) * 8);
            const bf16x8 bhi = *(const bf16x8*)(Qb + (r * 8 + ((4 + quad) ^ (r & 7))) * 8);
            const float lv = (qt + r < Lb) ? Lb_[r] : 0.f;
            f32x4 c0 = {0.f, 0.f, 0.f, 0.f}, c1 = {0.f, 0.f, 0.f, 0.f};
            c0 = __builtin_amdgcn_mfma_f32_16x16x32_bf16(a0lo, blo, c0, 0, 0, 0);
            c0 = __builtin_amdgcn_mfma_f32_16x16x32_bf16(a0hi, bhi, c0, 0, 0, 0);
            c1 = __builtin_amdgcn_mfma_f32_16x16x32_bf16(a1lo, blo, c1, 0, 0, 0);
            c1 = __builtin_amdgcn_mfma_f32_16x16x32_bf16(a1hi, bhi, c1, 0, 0, 0);
            #pragma unroll
            for (int rr = 0; rr < 4; ++rr) {
                w0[rr] += __expf(c0[rr]) * lv;
                w1[rr] += __expf(c1[rr]) * lv;
            }
        }
    }
    #pragma unroll
    for (int off = 1; off <= 8; off <<= 1) {
        #pragma unroll
        for (int rr = 0; rr < 4; ++rr) {
            w0[rr] += __shfl_xor(w0[rr], off, 64);
            w1[rr] += __shfl_xor(w1[rr], off, 64);
        }
    }
    if (l16 == 0) {
        float* __restrict__ cp = ws + CPOFF + ((size_t)blockIdx.z * 64 + bh) * Sc;
        #pragma unroll
        for (int rr = 0; rr < 4; ++rr) {
            cp[k0 + quad * 4 + rr]      = w0[rr];
            cp[k0 + 16 + quad * 4 + rr] = w1[rr];
        }
    }
}

// ---------------------------------------------------------------------------
// Kernel 3b: warr[k] = sum over valid q-chunks of cp.
// ---------------------------------------------------------------------------
__global__ __launch_bounds__(256) void colsum_reduce_kernel(
    const int* __restrict__ L, float* __restrict__ ws)
{
    const int bh = blockIdx.y;
    const int k  = blockIdx.x * 256 + threadIdx.x;
    const int nc = (L[bh >> 4] + 511) >> 9;
    float acc = 0.f;
    for (int c = 0; c < nc; ++c)
        acc += ws[CPOFF + ((size_t)c * 64 + bh) * Sc + k];
    ws[WOFF + (size_t)bh * Sc + k] = acc;
}

// ---------------------------------------------------------------------------
// Kernel 4a: partial y: yp[c][b,h,j] = sum_{s in chunk c} w[b,h,s]*x[b,s,j].
// ---------------------------------------------------------------------------
__global__ __launch_bounds__(256) void yw_part_kernel(
    const float* __restrict__ x, const int* __restrict__ L,
    float* __restrict__ ws)
{
    const int b  = blockIdx.y;
    const int j0 = blockIdx.x * 64;
    const int s0 = blockIdx.z * 128;
    const int Lb = L[b];
    if (s0 >= Lb) return;
    const int js = threadIdx.x & 63;
    const int sl = threadIdx.x >> 6;
    const float* __restrict__ warr = ws + WOFF + (size_t)b * NHc * Sc;
    const float* __restrict__ xb = x + (size_t)b * Sc * Hc;

    __shared__ float wt[128][20];
    __shared__ float red[4][16][64];

    #pragma unroll
    for (int i = 0; i < 8; ++i) {
        const int s = (threadIdx.x & 15) + 16 * i;
        const int h = threadIdx.x >> 4;
        float v = 0.f;
        if (s0 + s < Lb) v = warr[(size_t)h * Sc + s0 + s];
        wt[s][h] = v;
    }
    __syncthreads();

    float acc[16];
    #pragma unroll
    for (int h = 0; h < 16; ++h) acc[h] = 0.f;

    #pragma unroll 4
    for (int s = sl; s < 128; s += 4) {
        const float xv = xb[(size_t)(s0 + s) * Hc + j0 + js];
        const f32x4 wa = *(const f32x4*)&wt[s][0];
        const f32x4 wb = *(const f32x4*)&wt[s][4];
        const f32x4 wc = *(const f32x4*)&wt[s][8];
        const f32x4 wd = *(const f32x4*)&wt[s][12];
        #pragma unroll
        for (int h = 0; h < 4; ++h) acc[h]      += wa[h] * xv;
        #pragma unroll
        for (int h = 0; h < 4; ++h) acc[4 + h]  += wb[h] * xv;
        #pragma unroll
        for (int h = 0; h < 4; ++h) acc[8 + h]  += wc[h] * xv;
        #pragma unroll
        for (int h = 0; h < 4; ++h) acc[12 + h] += wd[h] * xv;
    }
    #pragma unroll
    for (int h = 0; h < 16; ++h) red[sl][h][js] = acc[h];
    __syncthreads();
    if (sl == 0) {
        float* __restrict__ yp = ws + YPOFF +
            ((size_t)blockIdx.z * Bc * NHc + (size_t)b * NHc) * Hc;
        #pragma unroll
        for (int h = 0; h < 16; ++h)
            yp[(size_t)h * Hc + j0 + js] =
                red[0][h][js] + red[1][h][js] + red[2][h][js] + red[3][h][js];
    }
}

// ---------------------------------------------------------------------------
// Kernel 4b: y[b,h,j] = sum over valid chunks of yp.
// ---------------------------------------------------------------------------
__global__ __launch_bounds__(256) void yw_reduce_kernel(
    const int* __restrict__ L, float* __restrict__ ws)
{
    const int b = blockIdx.y;
    const int i = blockIdx.x * 256 + threadIdx.x;   // over NHc*Hc = 16384
    const int nc = (L[b] + 127) >> 7;
    const float* __restrict__ p = ws + YPOFF + (size_t)b * NHc * Hc + i;
    float acc = 0.f;
    for (int c = 0; c < nc; ++c)
        acc += p[(size_t)c * Bc * NHc * Hc];
    ws[YOFF + (size_t)b * NHc * Hc + i] = acc;
}

// ---------------------------------------------------------------------------
// Kernel 5: csum[b,n] = sum_j y[b,h(n),j]*Wv[n,j] + bv[n]*L[b].
// Wave-per-row coalesced GEMV.
// ---------------------------------------------------------------------------
__global__ __launch_bounds__(256) void csum_kernel(
    const float* __restrict__ Wv, const float* __restrict__ bv,
    const int* __restrict__ L, float* __restrict__ ws)
{
    const int b = blockIdx.y;
    const int h = blockIdx.x;
    const int n0 = h * 64;
    const int lane = threadIdx.x & 63;
    const int wave = threadIdx.x >> 6;
    const float Lb = (float)L[b];

    __shared__ float ys[1024];
    const float* __restrict__ y = ws + YOFF + ((size_t)b * NHc + h) * Hc;
    for (int i = threadIdx.x; i < 1024; i += 256) ys[i] = y[i];
    __syncthreads();

    f32x4 yv[4];
    #pragma unroll
    for (int p = 0; p < 4; ++p) yv[p] = *(const f32x4*)&ys[p * 256 + lane * 4];

    #pragma unroll
    for (int r = 0; r < 16; ++r) {
        const int n = n0 + wave * 16 + r;
        const float* wrow = Wv + (size_t)n * Hc;
        float a = 0.f;
        #pragma unroll
        for (int p = 0; p < 4; ++p) {
            const f32x4 wv = *(const f32x4*)(wrow + p * 256 + lane * 4);
            a += wv[0]*yv[p][0] + wv[1]*yv[p][1] + wv[2]*yv[p][2] + wv[3]*yv[p][3];
        }
        #pragma unroll
        for (int off = 32; off > 0; off >>= 1) a += __shfl_xor(a, off, 64);
        if (lane == 0)
            ws[CSOFF + (size_t)b * Hc + n] = a + bv[n] * Lb;
    }
}

// ---------------------------------------------------------------------------
// Kernel 6: pooled[b,o] = (sum_n csum[b,n]*Wo[o,n]) / L[b] + bo[o].
// ---------------------------------------------------------------------------
__global__ __launch_bounds__(256) void out_kernel(
    const float* __restrict__ Wo, const float* __restrict__ bo,
    const int* __restrict__ L, const float* __restrict__ ws,
    float* __restrict__ out)
{
    const int b = blockIdx.y;
    const int o0 = blockIdx.x * 64;
    const int lane = threadIdx.x & 63;
    const int wave = threadIdx.x >> 6;
    const float linv = 1.0f / (float)L[b];

    __shared__ float cs[1024];
    const float* __restrict__ c = ws + CSOFF + (size_t)b * Hc;
    for (int i = threadIdx.x; i < 1024; i += 256) cs[i] = c[i];
    __syncthreads();

    f32x4 cv[4];
    #pragma unroll
    for (int p = 0; p < 4; ++p) cv[p] = *(const f32x4*)&cs[p * 256 + lane * 4];

    #pragma unroll
    for (int r = 0; r < 16; ++r) {
        const int o = o0 + wave * 16 + r;
        const float* wrow = Wo + (size_t)o * Hc;
        float a = 0.f;
        #pragma unroll
        for (int p = 0; p < 4; ++p) {
            const f32x4 wv = *(const f32x4*)(wrow + p * 256 + lane * 4);
            a += wv[0]*cv[p][0] + wv[1]*cv[p][1] + wv[2]*cv[p][2] + wv[3]*cv[p][3];
        }
        #pragma unroll
        for (int off = 32; off > 0; off >>= 1) a += __shfl_xor(a, off, 64);
        if (lane == 0)
            out[(size_t)b * Hc + o] = a * linv + bo[o];
    }
}

// ---------------------------------------------------------------------------
extern "C" void kernel_launch(void* const* d_in, const int* in_sizes, int n_in,
                              void* d_out, int out_size, void* d_ws, size_t ws_size,
                              hipStream_t stream)
{
    (void)in_sizes; (void)n_in; (void)out_size; (void)ws_size;
    const float* x  = (const float*)d_in[0];
    const int*   L  = (const int*)d_in[1];
    const float* Wq = (const float*)d_in[2];
    const float* Wk = (const float*)d_in[3];
    const float* Wv = (const float*)d_in[4];
    const float* bv = (const float*)d_in[5];
    const float* Wo = (const float*)d_in[6];
    const float* bo = (const float*)d_in[7];
    float* out = (float*)d_out;
    float* ws  = (float*)d_ws;

    cvt_all_kernel<<<5120, 256, 0, stream>>>(x, Wq, Wk, ws);

    dim3 gp(Hc / 128, (Bc * Sc) / 128, 2);
    proj_mfma_kernel<<<gp, 256, 0, stream>>>(L, ws);

    dim3 gr(Bc * NHc, Sc / 128, 4);
    rowsum_part_kernel<<<gr, 256, 0, stream>>>(L, ws);
    dim3 grr(Sc / 256, Bc * NHc);
    rowsum_reduce_kernel<<<grr, 256, 0, stream>>>(L, ws);

    dim3 gcp(Bc * NHc, Sc / 128, 4);
    colsum_part_kernel<<<gcp, 256, 0, stream>>>(L, ws);
    colsum_reduce_kernel<<<grr, 256, 0, stream>>>(L, ws);

    dim3 gy(Hc / 64, Bc, Sc / 128);
    yw_part_kernel<<<gy, 256, 0, stream>>>(x, L, ws);

    dim3 gyr((NHc * Hc) / 256, Bc);
    yw_reduce_kernel<<<gyr, 256, 0, stream>>>(L, ws);

    dim3 gc(NHc, Bc);
    csum_kernel<<<gc, 256, 0, stream>>>(Wv, bv, L, ws);

    dim3 go(Hc / 64, Bc);
    out_kernel<<<go, 256, 0, stream>>>(Wo, bo, L, ws, out);
}